// Round 5
// baseline (586.092 us; speedup 1.0000x reference)
//
#include <hip/hip_runtime.h>

#define NN 50000
#define NE 500000
#define HD 128
#define HD2 256
#define NL 4
#define NG 1000

constexpr float MSG_EPS = 1e-7f;
constexpr float LNEPS   = 1e-5f;

typedef float  f32x4  __attribute__((ext_vector_type(4)));
typedef __bf16 bf16x8 __attribute__((ext_vector_type(8)));

__device__ __forceinline__ unsigned short f2b(float f) {
    unsigned int u = __float_as_uint(f);
    unsigned int r = u + 0x7FFFu + ((u >> 16) & 1u);
    return (unsigned short)(r >> 16);
}
__device__ __forceinline__ float b2f(unsigned short h) {
    return __uint_as_float(((unsigned int)h) << 16);
}

// ---------------- node encoder: z0 = bf16(x @ Wn + bn) ----------------
__global__ void k_encode_nodes(const float* __restrict__ x, const float* __restrict__ W,
                               const float* __restrict__ b, unsigned short* __restrict__ zb) {
    int n = blockIdx.x;
    int c = threadIdx.x;  // 128
    float xr[9];
#pragma unroll
    for (int k = 0; k < 9; k++) xr[k] = x[n * 9 + k];
    float acc = b[c];
#pragma unroll
    for (int k = 0; k < 9; k++) acc = fmaf(xr[k], W[k * HD + c], acc);
    zb[n * HD + c] = f2b(acc);
}

// ---------------- weight prep: fp32 -> bf16 transposed ----------------
__global__ void k_prep(const float* __restrict__ W1, const float* __restrict__ W2,
                       unsigned short* __restrict__ W1T, unsigned short* __restrict__ W2T) {
    int idx = blockIdx.x * 256 + threadIdx.x;  // 131072 total
    {
        int k = idx & 127, n = (idx >> 7) & 255, l = idx >> 15;
        W1T[idx] = f2b(W1[(l * 128 + k) * 256 + n]);
    }
    {
        int k = idx & 255, n = (idx >> 8) & 127, l = idx >> 15;
        W2T[idx] = f2b(W2[(l * 256 + k) * 128 + n]);
    }
}

// ---------------- CSR build ----------------
__global__ void k_hist(const int* __restrict__ dst, int* __restrict__ counts) {
    int e = blockIdx.x * blockDim.x + threadIdx.x;
    if (e < NE) atomicAdd(&counts[dst[e]], 1);
}

#define SCAN_B 512
__global__ void k_scan1(const int* __restrict__ counts, int* __restrict__ incl,
                        int* __restrict__ bsum) {
    __shared__ int s[SCAN_B];
    int i = blockIdx.x * SCAN_B + threadIdx.x;
    int v = (i < NN) ? counts[i] : 0;
    s[threadIdx.x] = v;
    __syncthreads();
    for (int off = 1; off < SCAN_B; off <<= 1) {
        int t = (threadIdx.x >= off) ? s[threadIdx.x - off] : 0;
        __syncthreads();
        s[threadIdx.x] += t;
        __syncthreads();
    }
    if (i < NN) incl[i] = s[threadIdx.x];
    if (threadIdx.x == SCAN_B - 1) bsum[blockIdx.x] = s[threadIdx.x];
}

__global__ void k_scan2(const int* __restrict__ bsum, int* __restrict__ boff, int nb) {
    __shared__ int s[128];
    int v = (threadIdx.x < nb) ? bsum[threadIdx.x] : 0;
    s[threadIdx.x] = v;
    __syncthreads();
    for (int off = 1; off < 128; off <<= 1) {
        int t = (threadIdx.x >= off) ? s[threadIdx.x - off] : 0;
        __syncthreads();
        s[threadIdx.x] += t;
        __syncthreads();
    }
    if (threadIdx.x < nb) boff[threadIdx.x] = s[threadIdx.x] - v;  // exclusive
}

__global__ void k_scan3(const int* __restrict__ incl, const int* __restrict__ boff,
                        int* __restrict__ row_start) {
    int i = blockIdx.x * SCAN_B + threadIdx.x;
    if (i < NN) row_start[i + 1] = incl[i] + boff[blockIdx.x];
    if (i == 0) row_start[0] = 0;
}

// pack {attr0, attr1, attr2, src} per CSR slot
__global__ void k_scatter(const int* __restrict__ src, const int* __restrict__ dst,
                          const float* __restrict__ eattr, const int* __restrict__ row_start,
                          int* __restrict__ cursor, float4* __restrict__ aperm) {
    int e = blockIdx.x * blockDim.x + threadIdx.x;
    if (e >= NE) return;
    int d = dst[e];
    int p = row_start[d] + atomicAdd(&cursor[d], 1);
    float4 v;
    v.x = eattr[e * 3 + 0];
    v.y = eattr[e * 3 + 1];
    v.z = eattr[e * 3 + 2];
    v.w = __int_as_float(src[e]);
    aperm[p] = v;
}

// ---------------- softmax aggregation: one wave per node, lane owns 2 channels ----
__global__ __launch_bounds__(256) void k_aggregate(const unsigned short* __restrict__ zb,
                                                   const float4* __restrict__ aperm,
                                                   const int* __restrict__ row_start,
                                                   const float* __restrict__ We,
                                                   const float* __restrict__ be,
                                                   const float* __restrict__ t, int layer,
                                                   unsigned int* __restrict__ outb) {
    int w = threadIdx.x >> 6, lane = threadIdx.x & 63;
    int n = blockIdx.x * 4 + w;
    if (n >= NN) return;
    int c = lane * 2;
    float2 w0 = *(const float2*)&We[c];
    float2 w1 = *(const float2*)&We[HD + c];
    float2 w2 = *(const float2*)&We[2 * HD + c];
    float2 bb = *(const float2*)&be[c];
    float tv = t[layer];
    int s0 = row_start[n], s1 = row_start[n + 1];
    float num0 = 0.f, num1 = 0.f, wm0 = 0.f, wm1 = 0.f;
    const unsigned int* z32 = (const unsigned int*)zb;
    int p = s0;
    for (; p + 2 <= s1; p += 2) {
        float4 a0 = aperm[p];
        float4 a1 = aperm[p + 1];
        int sj0 = __float_as_int(a0.w);
        int sj1 = __float_as_int(a1.w);
        unsigned int za = z32[sj0 * 64 + lane];
        unsigned int zc = z32[sj1 * 64 + lane];
        float zax = b2f((unsigned short)za), zay = b2f((unsigned short)(za >> 16));
        float zcx = b2f((unsigned short)zc), zcy = b2f((unsigned short)(zc >> 16));
        float ea0x = fmaf(a0.x, w0.x, fmaf(a0.y, w1.x, fmaf(a0.z, w2.x, bb.x)));
        float ea0y = fmaf(a0.x, w0.y, fmaf(a0.y, w1.y, fmaf(a0.z, w2.y, bb.y)));
        float ea1x = fmaf(a1.x, w0.x, fmaf(a1.y, w1.x, fmaf(a1.z, w2.x, bb.x)));
        float ea1y = fmaf(a1.x, w0.y, fmaf(a1.y, w1.y, fmaf(a1.z, w2.y, bb.y)));
        float m0x = fmaxf(zax + ea0x, 0.f) + MSG_EPS;
        float m0y = fmaxf(zay + ea0y, 0.f) + MSG_EPS;
        float m1x = fmaxf(zcx + ea1x, 0.f) + MSG_EPS;
        float m1y = fmaxf(zcy + ea1y, 0.f) + MSG_EPS;
        float e0x = __expf(tv * m0x), e0y = __expf(tv * m0y);
        float e1x = __expf(tv * m1x), e1y = __expf(tv * m1y);
        num0 += e0x + e1x;
        num1 += e0y + e1y;
        wm0 = fmaf(m0x, e0x, fmaf(m1x, e1x, wm0));
        wm1 = fmaf(m0y, e0y, fmaf(m1y, e1y, wm1));
    }
    if (p < s1) {
        float4 a = aperm[p];
        int sj = __float_as_int(a.w);
        unsigned int za = z32[sj * 64 + lane];
        float zax = b2f((unsigned short)za), zay = b2f((unsigned short)(za >> 16));
        float eax = fmaf(a.x, w0.x, fmaf(a.y, w1.x, fmaf(a.z, w2.x, bb.x)));
        float eay = fmaf(a.x, w0.y, fmaf(a.y, w1.y, fmaf(a.z, w2.y, bb.y)));
        float mx = fmaxf(zax + eax, 0.f) + MSG_EPS;
        float my = fmaxf(zay + eay, 0.f) + MSG_EPS;
        float ex = __expf(tv * mx), ey = __expf(tv * my);
        num0 += ex;
        num1 += ey;
        wm0 = fmaf(mx, ex, wm0);
        wm1 = fmaf(my, ey, wm1);
    }
    unsigned int zn = z32[n * 64 + lane];
    float ox = ((s1 > s0) ? (wm0 / num0) : 0.f) + b2f((unsigned short)zn);
    float oy = ((s1 > s0) ? (wm1 / num1) : 0.f) + b2f((unsigned short)(zn >> 16));
    outb[n * 64 + lane] = (unsigned int)f2b(ox) | ((unsigned int)f2b(oy) << 16);
}

// ---------------- fused MFMA MLP, barrier-free: one wave owns 16 rows fully ----------
// hnew = (add? h : 0) + relu(LN(A@W1+b1))@W2+b2 ;  h=bf16(hnew) ; zb=bf16(relu(LN_next(hnew)))
// grid = 3125 blocks x 64 threads (one wave, rows base..base+15). No __syncthreads.
// LN in-register: stats over cols = sum over ct regs + 4-step xor-shuffle in 16-lane group.
// LDS only for the C-layout -> A-layout transpose of the hidden tile (per-wave private).
#define HS_LD 268  // 16-row bf16 tile stride: quads map to disjoint bank groups on pack-store

__global__ __launch_bounds__(64) void k_mlp(const unsigned short* __restrict__ outb,
                                            const unsigned short* __restrict__ W1T,
                                            const float* __restrict__ b1l,
                                            const float* __restrict__ lgl,
                                            const float* __restrict__ lbl,
                                            const unsigned short* __restrict__ W2T,
                                            const float* __restrict__ b2l,
                                            unsigned short* __restrict__ h,
                                            const float* __restrict__ gn,
                                            const float* __restrict__ bn,
                                            unsigned short* __restrict__ zb,
                                            int add_residual) {
    __shared__ __align__(16) unsigned short Hs[16 * HS_LD];  // 8576 B

    int base = blockIdx.x * 16;
    int lane = threadIdx.x;  // 0..63
    int q = lane >> 4, i = lane & 15;

    // ---- GEMM1: 16 rows x 256 cols, K=128; A direct from global bf16 ----
    f32x4 acc[16];
#pragma unroll
    for (int ct = 0; ct < 16; ct++) acc[ct] = (f32x4){0.f, 0.f, 0.f, 0.f};

#pragma unroll
    for (int ks = 0; ks < 4; ks++) {
        bf16x8 a = *(const bf16x8*)&outb[(size_t)(base + i) * HD + ks * 32 + q * 8];
#pragma unroll
        for (int ct = 0; ct < 16; ct++) {
            bf16x8 bfr = *(const bf16x8*)&W1T[(ct * 16 + i) * HD + ks * 32 + q * 8];
            acc[ct] = __builtin_amdgcn_mfma_f32_16x16x32_bf16(a, bfr, acc[ct], 0, 0, 0);
        }
    }

    // ---- +b1 ----
#pragma unroll
    for (int ct = 0; ct < 16; ct++) {
        float bb = b1l[ct * 16 + i];
#pragma unroll
        for (int r = 0; r < 4; r++) acc[ct][r] += bb;
    }

    // ---- LN(256) in-register; lane holds rows q*4+r, cols ct*16+i ----
    {
        float s[4] = {0.f, 0.f, 0.f, 0.f}, sq[4] = {0.f, 0.f, 0.f, 0.f};
#pragma unroll
        for (int ct = 0; ct < 16; ct++)
#pragma unroll
            for (int r = 0; r < 4; r++) {
                s[r] += acc[ct][r];
                sq[r] = fmaf(acc[ct][r], acc[ct][r], sq[r]);
            }
#pragma unroll
        for (int m = 8; m >= 1; m >>= 1)
#pragma unroll
            for (int r = 0; r < 4; r++) {
                s[r] += __shfl_xor(s[r], m);
                sq[r] += __shfl_xor(sq[r], m);
            }
        float mu[4], inv[4];
#pragma unroll
        for (int r = 0; r < 4; r++) {
            mu[r] = s[r] * (1.f / 256.f);
            float var = sq[r] * (1.f / 256.f) - mu[r] * mu[r];
            inv[r] = rsqrtf(var + LNEPS);
        }
        // relu + pack bf16 -> LDS (row q*4+r, col ct*16+i)
#pragma unroll
        for (int ct = 0; ct < 16; ct++) {
            float g = lgl[ct * 16 + i];
            float c = lbl[ct * 16 + i];
#pragma unroll
            for (int r = 0; r < 4; r++) {
                float v = fmaxf(fmaf((acc[ct][r] - mu[r]) * inv[r], g, c), 0.f);
                Hs[(q * 4 + r) * HS_LD + ct * 16 + i] = f2b(v);
            }
        }
    }
    // same-wave ds_write -> ds_read: compiler inserts lgkmcnt wait; no barrier needed

    // ---- GEMM2: 16 rows x 128 cols, K=256 ----
    f32x4 acc2[8];
#pragma unroll
    for (int ct = 0; ct < 8; ct++) acc2[ct] = (f32x4){0.f, 0.f, 0.f, 0.f};

#pragma unroll
    for (int ks = 0; ks < 8; ks++) {
        bf16x8 a = *(const bf16x8*)&Hs[i * HS_LD + ks * 32 + q * 8];
#pragma unroll
        for (int ct = 0; ct < 8; ct++) {
            bf16x8 bfr = *(const bf16x8*)&W2T[(ct * 16 + i) * HD2 + ks * 32 + q * 8];
            acc2[ct] = __builtin_amdgcn_mfma_f32_16x16x32_bf16(a, bfr, acc2[ct], 0, 0, 0);
        }
    }

    // ---- hn = acc2 + b2 + (add? h_old : 0); store h bf16 ----
    if (add_residual) {
#pragma unroll
        for (int ct = 0; ct < 8; ct++) {
            float bb = b2l[ct * 16 + i];
#pragma unroll
            for (int r = 0; r < 4; r++) {
                size_t idx = (size_t)(base + q * 4 + r) * HD + ct * 16 + i;
                acc2[ct][r] += bb + b2f(h[idx]);
            }
        }
    } else {
#pragma unroll
        for (int ct = 0; ct < 8; ct++) {
            float bb = b2l[ct * 16 + i];
#pragma unroll
            for (int r = 0; r < 4; r++) acc2[ct][r] += bb;
        }
    }
#pragma unroll
    for (int ct = 0; ct < 8; ct++)
#pragma unroll
        for (int r = 0; r < 4; r++) {
            size_t idx = (size_t)(base + q * 4 + r) * HD + ct * 16 + i;
            h[idx] = f2b(acc2[ct][r]);
        }

    // ---- LN(128) in-register + relu -> zb ----
    {
        float s[4] = {0.f, 0.f, 0.f, 0.f}, sq[4] = {0.f, 0.f, 0.f, 0.f};
#pragma unroll
        for (int ct = 0; ct < 8; ct++)
#pragma unroll
            for (int r = 0; r < 4; r++) {
                s[r] += acc2[ct][r];
                sq[r] = fmaf(acc2[ct][r], acc2[ct][r], sq[r]);
            }
#pragma unroll
        for (int m = 8; m >= 1; m >>= 1)
#pragma unroll
            for (int r = 0; r < 4; r++) {
                s[r] += __shfl_xor(s[r], m);
                sq[r] += __shfl_xor(sq[r], m);
            }
        float mu[4], inv[4];
#pragma unroll
        for (int r = 0; r < 4; r++) {
            mu[r] = s[r] * (1.f / 128.f);
            float var = sq[r] * (1.f / 128.f) - mu[r] * mu[r];
            inv[r] = rsqrtf(var + LNEPS);
        }
#pragma unroll
        for (int ct = 0; ct < 8; ct++) {
            float g = gn[ct * 16 + i];
            float c = bn[ct * 16 + i];
#pragma unroll
            for (int r = 0; r < 4; r++) {
                float v = fmaxf(fmaf((acc2[ct][r] - mu[r]) * inv[r], g, c), 0.f);
                zb[(size_t)(base + q * 4 + r) * HD + ct * 16 + i] = f2b(v);
            }
        }
    }
}

// ---------------- atomic-free global mean pool (batch is sorted) ----------------
__global__ void k_gbounds(const int* __restrict__ batch, int* __restrict__ gstart) {
    int g = blockIdx.x * blockDim.x + threadIdx.x;
    if (g > NG) return;
    int lo = 0, hi = NN;
    while (lo < hi) {
        int mid = (lo + hi) >> 1;
        if (batch[mid] < g) lo = mid + 1;
        else hi = mid;
    }
    gstart[g] = lo;
}

__global__ void k_pool(const unsigned short* __restrict__ zb, const int* __restrict__ gstart,
                       float* __restrict__ out) {
    int g = blockIdx.x;
    int c = threadIdx.x;  // 128
    int a = gstart[g], b = gstart[g + 1];
    float s0 = 0.f, s1 = 0.f;
    int n = a;
    for (; n + 2 <= b; n += 2) {
        s0 += b2f(zb[(size_t)n * HD + c]);
        s1 += b2f(zb[(size_t)(n + 1) * HD + c]);
    }
    if (n < b) s0 += b2f(zb[(size_t)n * HD + c]);
    out[g * HD + c] = (s0 + s1) / fmaxf((float)(b - a), 1.f);
}

// ---------------- launch ----------------
extern "C" void kernel_launch(void* const* d_in, const int* in_sizes, int n_in, void* d_out,
                              int out_size, void* d_ws, size_t ws_size, hipStream_t stream) {
    const float* x     = (const float*)d_in[0];
    const int* ei      = (const int*)d_in[1];
    const float* eattr = (const float*)d_in[2];
    const int* batch   = (const int*)d_in[3];
    const float* encW  = (const float*)d_in[4];
    const float* encB  = (const float*)d_in[5];
    const float* eW    = (const float*)d_in[6];
    const float* eB    = (const float*)d_in[7];
    const float* ln_g  = (const float*)d_in[8];
    const float* ln_b  = (const float*)d_in[9];
    const float* W1    = (const float*)d_in[10];
    const float* b1    = (const float*)d_in[11];
    const float* mlg   = (const float*)d_in[12];
    const float* mlb   = (const float*)d_in[13];
    const float* W2    = (const float*)d_in[14];
    const float* b2    = (const float*)d_in[15];
    const float* t     = (const float*)d_in[16];
    const int* src = ei;
    const int* dst = ei + NE;

    char* w = (char*)d_ws;
    auto alloc = [&](size_t bytes) {
        char* p = w;
        w += (bytes + 255) & ~size_t(255);
        return p;
    };
    unsigned short* h    = (unsigned short*)alloc(sizeof(unsigned short) * NN * HD);
    unsigned short* zb   = (unsigned short*)alloc(sizeof(unsigned short) * NN * HD);
    unsigned int* outb   = (unsigned int*)alloc(sizeof(unsigned int) * NN * HD / 2);
    float4* aperm        = (float4*)alloc(sizeof(float4) * NE);
    int* row_start       = (int*)alloc(sizeof(int) * (NN + 1));
    int* counts          = (int*)alloc(sizeof(int) * NN);
    int* cursor          = (int*)alloc(sizeof(int) * NN);
    int* incl            = (int*)alloc(sizeof(int) * NN);
    int* bsum            = (int*)alloc(sizeof(int) * 128);
    int* boff            = (int*)alloc(sizeof(int) * 128);
    int* gstart          = (int*)alloc(sizeof(int) * (NG + 1));
    unsigned short* W1T  = (unsigned short*)alloc(sizeof(unsigned short) * NL * HD * HD2);
    unsigned short* W2T  = (unsigned short*)alloc(sizeof(unsigned short) * NL * HD2 * HD);

    hipMemsetAsync(counts, 0, sizeof(int) * NN, stream);
    hipMemsetAsync(cursor, 0, sizeof(int) * NN, stream);

    k_prep<<<512, 256, 0, stream>>>(W1, W2, W1T, W2T);
    k_encode_nodes<<<NN, HD, 0, stream>>>(x, encW, encB, zb);
    k_hist<<<(NE + 255) / 256, 256, 0, stream>>>(dst, counts);
    int nsb = (NN + SCAN_B - 1) / SCAN_B;
    k_scan1<<<nsb, SCAN_B, 0, stream>>>(counts, incl, bsum);
    k_scan2<<<1, 128, 0, stream>>>(bsum, boff, nsb);
    k_scan3<<<nsb, SCAN_B, 0, stream>>>(incl, boff, row_start);
    k_scatter<<<(NE + 255) / 256, 256, 0, stream>>>(src, dst, eattr, row_start, cursor, aperm);
    k_gbounds<<<(NG + 256) / 256, 256, 0, stream>>>(batch, gstart);

    for (int l = 0; l < NL; l++) {
        k_aggregate<<<(NN + 3) / 4, 256, 0, stream>>>(zb, aperm, row_start, eW, eB, t, l, outb);
        int ln_next = (l + 1) % NL;  // layer 3 fuses the final ln (reuses layer-0 params)
        k_mlp<<<NN / 16, 64, 0, stream>>>(
            (const unsigned short*)outb, W1T + (size_t)l * HD * HD2, b1 + l * HD2,
            mlg + l * HD2, mlb + l * HD2, W2T + (size_t)l * HD2 * HD, b2 + l * HD, h,
            ln_g + ln_next * HD, ln_b + ln_next * HD, zb, l > 0);
    }
    k_pool<<<NG, HD, 0, stream>>>(zb, gstart, (float*)d_out);
}